// Round 2
// baseline (775.441 us; speedup 1.0000x reference)
//
#include <hip/hip_runtime.h>
#include <hip/hip_bf16.h>

#define B_ 8
#define N_ 4096
#define D_ 1024

// ---------------------------------------------------------------------------
// K0: prep. blocks 0..15: qk[r] = (l2norm(layernorm(phi[r]*qg+qb))) ⊙ kg,
//                         cj[r] = Σ q·kb.   block 16: w2=kg², w1=2kg·kb, C=Σkb².
// ---------------------------------------------------------------------------
__global__ __launch_bounds__(64) void k_prep(
    const float* __restrict__ phi, const float* __restrict__ qg, const float* __restrict__ qb,
    const float* __restrict__ lng, const float* __restrict__ lnb,
    const float* __restrict__ kg, const float* __restrict__ kb,
    float* __restrict__ qk, float* __restrict__ cj, float* __restrict__ wbuf)
{
    int r = blockIdx.x;        // 0..16
    int lane = threadIdx.x;    // 0..63
    if (r == 16) {
        float cacc = 0.f;
#pragma unroll
        for (int c = 0; c < 16; ++c) {
            int i = c * 64 + lane;
            float g = kg[i], b = kb[i];
            wbuf[i] = g * g;
            wbuf[1024 + i] = 2.0f * g * b;
            cacc += b * b;
        }
#pragma unroll
        for (int m = 32; m; m >>= 1) cacc += __shfl_xor(cacc, m);
        if (lane == 0) wbuf[2048] = cacc;
        return;
    }
    const float* pr = phi + (size_t)r * D_;
    float v[16];
    float s1 = 0.f;
#pragma unroll
    for (int c = 0; c < 16; ++c) {
        int i = c * 64 + lane;
        v[c] = pr[i] * qg[i] + qb[i];
        s1 += v[c];
    }
#pragma unroll
    for (int m = 32; m; m >>= 1) s1 += __shfl_xor(s1, m);
    float mu = s1 * (1.0f / D_);
    float s2 = 0.f;
#pragma unroll
    for (int c = 0; c < 16; ++c) { float dd = v[c] - mu; s2 += dd * dd; }
#pragma unroll
    for (int m = 32; m; m >>= 1) s2 += __shfl_xor(s2, m);
    float var = s2 * (1.0f / D_);
    float inv = 1.0f / sqrtf(var + 1e-5f);
    float u[16];
    float s3 = 0.f;
#pragma unroll
    for (int c = 0; c < 16; ++c) {
        int i = c * 64 + lane;
        u[c] = (v[c] - mu) * inv * lng[i] + lnb[i];
        s3 += u[c] * u[c];
    }
#pragma unroll
    for (int m = 32; m; m >>= 1) s3 += __shfl_xor(s3, m);
    float rn = 1.0f / (sqrtf(s3) + 1e-6f);
    float cacc = 0.f;
#pragma unroll
    for (int c = 0; c < 16; ++c) {
        int i = c * 64 + lane;
        float qv = u[c] * rn;
        qk[(size_t)r * D_ + i] = qv * kg[i];
        cacc += qv * kb[i];
    }
#pragma unroll
    for (int m = 32; m; m >>= 1) cacc += __shfl_xor(cacc, m);
    if (lane == 0) cj[r] = cacc;
}

// ---------------------------------------------------------------------------
// K1: routing. Thread-per-token skinny GEMM: 32 tokens x 8 d-splits per block,
// double-buffered LDS x-tile (stride 68, conflict-free b128), uniform qk reads,
// no cross-lane ops in the hot loop. Epilogue: softmax (8 core experts; occ
// experts underflow to exact 0) + exact 16-way entmax15.
// ---------------------------------------------------------------------------
__global__ __launch_bounds__(256, 4) void k_route2(
    const float* __restrict__ x, const float* __restrict__ qk,
    const float* __restrict__ cj, const float* __restrict__ wbuf,
    const float* __restrict__ s0p, const float* __restrict__ s1p,
    float* __restrict__ combine, float* __restrict__ dispatch)
{
    __shared__ float xs[2][32 * 68];   // 2 x 8.5 KB
    __shared__ float qs[2][16 * 64];   // 2 x 4 KB
    __shared__ float wsd[2][128];      // w2 chunk | w1 chunk

    int tid = threadIdx.x;
    int tok0 = blockIdx.x * 32;
    int tok = tid & 31, gg = tid >> 5;           // gg = 0..7

    float acc[17];
#pragma unroll
    for (int v = 0; v < 17; ++v) acc[v] = 0.f;

    float4 rx0, rx1, rq;
    float rw = 0.f;
    int r0 = tid >> 4, c40 = tid & 15;           // idx0 = tid      -> rows 0..15
    int r1 = 16 + r0;                            // idx1 = 256+tid  -> rows 16..31

    // ---- stage chunk dc into registers ----
    auto STAGE = [&](int dc) {
        rx0 = *(const float4*)(x + (size_t)(tok0 + r0) * D_ + dc * 64 + c40 * 4);
        rx1 = *(const float4*)(x + (size_t)(tok0 + r1) * D_ + dc * 64 + c40 * 4);
        rq  = *(const float4*)(qk + (size_t)(tid >> 4) * D_ + dc * 64 + (tid & 15) * 4);
        if (tid < 128) rw = wbuf[(size_t)(tid >> 6) * 1024 + dc * 64 + (tid & 63)];
    };
    auto WRITE = [&](int buf) {
        *(float4*)(&xs[buf][r0 * 68 + c40 * 4]) = rx0;
        *(float4*)(&xs[buf][r1 * 68 + c40 * 4]) = rx1;
        ((float4*)qs[buf])[tid] = rq;
        if (tid < 128) wsd[buf][tid] = rw;
    };
    auto COMPUTE = [&](int buf) {
        const float* xp = &xs[buf][tok * 68 + gg * 8];
        const float* qp = &qs[buf][gg * 8];
        const float* wp = &wsd[buf][gg * 8];
#pragma unroll
        for (int dl4 = 0; dl4 < 2; ++dl4) {
            float4 xv  = *(const float4*)(xp + dl4 * 4);
            float4 w2v = *(const float4*)(wp + dl4 * 4);
            float4 w1v = *(const float4*)(wp + 64 + dl4 * 4);
            acc[16] += (w2v.x * xv.x + w1v.x) * xv.x + (w2v.y * xv.y + w1v.y) * xv.y
                     + (w2v.z * xv.z + w1v.z) * xv.z + (w2v.w * xv.w + w1v.w) * xv.w;
#pragma unroll
            for (int j = 0; j < 16; ++j) {
                float4 q4 = *(const float4*)(qp + j * 64 + dl4 * 4);
                acc[j] += xv.x * q4.x + xv.y * q4.y + xv.z * q4.z + xv.w * q4.w;
            }
        }
    };

    STAGE(0);
    WRITE(0);
    int cur = 0;
#pragma unroll 1
    for (int dc = 0; dc < 16; ++dc) {
        if (dc < 15) STAGE(dc + 1);
        __syncthreads();
        COMPUTE(cur);
        if (dc < 15) WRITE(cur ^ 1);
        cur ^= 1;
    }
    __syncthreads();

    // cross-split reduce in LDS: red[tok][v][gg], 32*17*8 = 4352 floats (= xs)
    float* red = &xs[0][0];
#pragma unroll
    for (int v = 0; v < 17; ++v) red[tok * 136 + v * 8 + gg] = acc[v];
    __syncthreads();

    if (tid < 32) {
        int t = tid;
        float s[17];
#pragma unroll
        for (int v = 0; v < 17; ++v) {
            float4 p0 = *(const float4*)(red + t * 136 + v * 8);
            float4 p1 = *(const float4*)(red + t * 136 + v * 8 + 4);
            s[v] = ((p0.x + p0.y) + (p0.z + p0.w)) + ((p1.x + p1.y) + (p1.z + p1.w));
        }
        float ss = s[16] + wbuf[2048];
        float rn = 1.0f / (sqrtf(ss) + 1e-6f);
        float inv0 = 1.0f / s0p[0];
        float inv1h = 0.5f / s1p[0];
        float lg[16];
#pragma unroll
        for (int j = 0; j < 16; ++j) lg[j] = (s[j] + cj[j]) * rn;

        // dispatch: softmax over 8 core experts per slot (occ = exact 0)
        float dsp[16];
#pragma unroll
        for (int sl = 0; sl < 2; ++sl) {
            float a[8], m = -1e30f;
#pragma unroll
            for (int ee = 0; ee < 8; ++ee) { a[ee] = lg[2 * ee + sl] * inv0; m = fmaxf(m, a[ee]); }
            float den = 0.f;
#pragma unroll
            for (int ee = 0; ee < 8; ++ee) { a[ee] = expf(a[ee] - m); den += a[ee]; }
            float r = 1.0f / den;
#pragma unroll
            for (int ee = 0; ee < 8; ++ee) dsp[2 * ee + sl] = a[ee] * r;
        }

        // combine: exact 1.5-entmax over 16 core slot logits
        float z[16], zmax = -1e30f;
#pragma unroll
        for (int j = 0; j < 16; ++j) { z[j] = lg[j] * inv1h; zmax = fmaxf(zmax, z[j]); }
#pragma unroll
        for (int j = 0; j < 16; ++j) z[j] -= zmax;
        float zsr[16];
#pragma unroll
        for (int j = 0; j < 16; ++j) zsr[j] = z[j];
#pragma unroll
        for (int rr = 0; rr < 16; ++rr) {
#pragma unroll
            for (int jj = (rr & 1); jj + 1 < 16; jj += 2) {
                float aa = zsr[jj], bb = zsr[jj + 1];
                zsr[jj] = fmaxf(aa, bb);
                zsr[jj + 1] = fminf(aa, bb);
            }
        }
        float cs = 0.f, css = 0.f, tau_star = 0.f;
#pragma unroll
        for (int kk = 1; kk <= 16; ++kk) {
            cs += zsr[kk - 1];
            css += zsr[kk - 1] * zsr[kk - 1];
            float fk = (float)kk;
            float mean = cs / fk, msq = css / fk;
            float ssv = fk * (msq - mean * mean);
            float delta = fmaxf((1.0f - ssv) / fk, 1e-12f);
            float tau = mean - sqrtf(delta);
            tau_star = (tau <= zsr[kk - 1]) ? tau : tau_star;
        }
        float4* cw = (float4*)(combine + (size_t)(tok0 + t) * 16);
        float4* dw = (float4*)(dispatch + (size_t)(tok0 + t) * 16);
#pragma unroll
        for (int q4i = 0; q4i < 4; ++q4i) {
            float4 cv, dv;
            float t0 = fmaxf(z[q4i * 4 + 0] - tau_star, 0.f);
            float t1 = fmaxf(z[q4i * 4 + 1] - tau_star, 0.f);
            float t2 = fmaxf(z[q4i * 4 + 2] - tau_star, 0.f);
            float t3 = fmaxf(z[q4i * 4 + 3] - tau_star, 0.f);
            cv.x = t0 * t0; cv.y = t1 * t1; cv.z = t2 * t2; cv.w = t3 * t3;
            dv.x = dsp[q4i * 4 + 0]; dv.y = dsp[q4i * 4 + 1];
            dv.z = dsp[q4i * 4 + 2]; dv.w = dsp[q4i * 4 + 3];
            cw[q4i] = cv;
            dw[q4i] = dv;
        }
    }
}

// ---------------------------------------------------------------------------
// K2b: partial slots. partial[b][nc][j][d] = sum_{n in chunk nc} disp[n][j]*x[b,n,d]
// ---------------------------------------------------------------------------
__global__ __launch_bounds__(256) void k_slots_partial(
    const float* __restrict__ x, const float* __restrict__ dispatch,
    float* __restrict__ partial)
{
    int nc = blockIdx.x, dc = blockIdx.y, b = blockIdx.z;
    int d = dc * 256 + threadIdx.x;
    const float* xb = x + (size_t)b * N_ * D_ + d;
    const float* db = dispatch + (size_t)b * N_ * 16;
    float acc[16];
#pragma unroll
    for (int j = 0; j < 16; ++j) acc[j] = 0.f;
    int n0 = nc * 256;
#pragma unroll 2
    for (int n = n0; n < n0 + 256; ++n) {
        float xv = xb[(size_t)n * D_];
        const float4* dp = (const float4*)(db + (size_t)n * 16);
        float4 q0 = dp[0], q1 = dp[1], q2 = dp[2], q3 = dp[3];
        acc[0]  += q0.x * xv; acc[1]  += q0.y * xv; acc[2]  += q0.z * xv; acc[3]  += q0.w * xv;
        acc[4]  += q1.x * xv; acc[5]  += q1.y * xv; acc[6]  += q1.z * xv; acc[7]  += q1.w * xv;
        acc[8]  += q2.x * xv; acc[9]  += q2.y * xv; acc[10] += q2.z * xv; acc[11] += q2.w * xv;
        acc[12] += q3.x * xv; acc[13] += q3.y * xv; acc[14] += q3.z * xv; acc[15] += q3.w * xv;
    }
#pragma unroll
    for (int j = 0; j < 16; ++j)
        partial[(((size_t)b * 16 + nc) * 16 + j) * 1024 + d] = acc[j];
}

// ---------------------------------------------------------------------------
// K2c: reduce partials -> slotsT[e][k][t]  (t = b*2+s)
// ---------------------------------------------------------------------------
__global__ __launch_bounds__(256) void k_slots_reduce(
    const float* __restrict__ partial, float* __restrict__ slotsT)
{
    int idx = blockIdx.x * 256 + threadIdx.x;   // 0..131071
    int t = idx & 15;
    int k = (idx >> 4) & 1023;
    int e = idx >> 14;
    int b = t >> 1, s = t & 1;
    int j = e * 2 + s;
    const float* p = partial + (((size_t)b * 16) * 16 + j) * 1024 + k;
    float sum = 0.f;
#pragma unroll
    for (int nc = 0; nc < 16; ++nc) sum += p[(size_t)nc * 16 * 1024];
    slotsT[idx] = sum;
}

// ---------------------------------------------------------------------------
// D1: h = gelu(slots @ w1 + b1), stored t-fast: hT[e][h][t]
// ---------------------------------------------------------------------------
__global__ __launch_bounds__(512) void k_mlp1(
    const float* __restrict__ w1, const float* __restrict__ b1,
    const float* __restrict__ slotsT, float* __restrict__ hT)
{
    int e = blockIdx.y;
    int col0 = blockIdx.x * 64;
    int tid = threadIdx.x;
    int cl = tid & 63;
    int p = tid >> 6;                 // 0..7
    const float* wp = w1 + ((size_t)e * 1024 + p * 128) * 4096 + col0 + cl;
    const float4* sp = (const float4*)(slotsT + ((size_t)e * 1024 + p * 128) * 16);
    float acc[16];
#pragma unroll
    for (int t = 0; t < 16; ++t) acc[t] = 0.f;
#pragma unroll 2
    for (int k = 0; k < 128; ++k) {
        float w = wp[(size_t)k * 4096];
        float4 a = sp[k * 4 + 0], bq = sp[k * 4 + 1], cq = sp[k * 4 + 2], dq = sp[k * 4 + 3];
        acc[0]  += w * a.x;  acc[1]  += w * a.y;  acc[2]  += w * a.z;  acc[3]  += w * a.w;
        acc[4]  += w * bq.x; acc[5]  += w * bq.y; acc[6]  += w * bq.z; acc[7]  += w * bq.w;
        acc[8]  += w * cq.x; acc[9]  += w * cq.y; acc[10] += w * cq.z; acc[11] += w * cq.w;
        acc[12] += w * dq.x; acc[13] += w * dq.y; acc[14] += w * dq.z; acc[15] += w * dq.w;
    }
    __shared__ float red[8 * 64 * 17];
#pragma unroll
    for (int t = 0; t < 16; ++t) red[(p * 64 + cl) * 17 + t] = acc[t];
    __syncthreads();
#pragma unroll
    for (int i = 0; i < 2; ++i) {
        int oi = tid + 512 * i;       // 0..1023
        int t = oi & 15, c = oi >> 4;
        float v = 0.f;
#pragma unroll
        for (int pp = 0; pp < 8; ++pp) v += red[(pp * 64 + c) * 17 + t];
        v += b1[(size_t)e * 4096 + col0 + c];
        v = 0.5f * v * (1.0f + erff(v * 0.70710678118654752f));   // exact GELU
        hT[((size_t)e * 4096 + col0 + c) * 16 + t] = v;
    }
}

// ---------------------------------------------------------------------------
// D2: core_out = h @ w2 + b2, stored co[b][j][d] (j = e*2+s)
// ---------------------------------------------------------------------------
__global__ __launch_bounds__(512) void k_mlp2(
    const float* __restrict__ w2, const float* __restrict__ b2,
    const float* __restrict__ hT, float* __restrict__ co)
{
    int e = blockIdx.y;
    int col0 = blockIdx.x * 32;
    int tid = threadIdx.x;
    int cl = tid & 31;
    int p = tid >> 5;                 // 0..15
    const float* wp = w2 + ((size_t)e * 4096 + p * 256) * 1024 + col0 + cl;
    const float4* hp = (const float4*)(hT + ((size_t)e * 4096 + p * 256) * 16);
    float acc[16];
#pragma unroll
    for (int t = 0; t < 16; ++t) acc[t] = 0.f;
#pragma unroll 2
    for (int k = 0; k < 256; ++k) {
        float w = wp[(size_t)k * 1024];
        float4 a = hp[k * 4 + 0], bq = hp[k * 4 + 1], cq = hp[k * 4 + 2], dq = hp[k * 4 + 3];
        acc[0]  += w * a.x;  acc[1]  += w * a.y;  acc[2]  += w * a.z;  acc[3]  += w * a.w;
        acc[4]  += w * bq.x; acc[5]  += w * bq.y; acc[6]  += w * bq.z; acc[7]  += w * bq.w;
        acc[8]  += w * cq.x; acc[9]  += w * cq.y; acc[10] += w * cq.z; acc[11] += w * cq.w;
        acc[12] += w * dq.x; acc[13] += w * dq.y; acc[14] += w * dq.z; acc[15] += w * dq.w;
    }
    __shared__ float red[16 * 32 * 17];
#pragma unroll
    for (int t = 0; t < 16; ++t) red[(p * 32 + cl) * 17 + t] = acc[t];
    __syncthreads();
    int c = tid & 31, t = tid >> 5;
    float v = 0.f;
#pragma unroll
    for (int pp = 0; pp < 16; ++pp) v += red[(pp * 32 + c) * 17 + t];
    v += b2[(size_t)e * 1024 + col0 + c];
    int bq2 = t >> 1, s = t & 1;
    co[(((size_t)bq2 * 16) + e * 2 + s) * 1024 + col0 + c] = v;
}

// ---------------------------------------------------------------------------
// KE: out[b,n,:] = sum_j combine[b,n,j] * co[b][j][:]
// ---------------------------------------------------------------------------
__global__ __launch_bounds__(256) void k_out(
    const float* __restrict__ co, const float* __restrict__ combine,
    float* __restrict__ out)
{
    int b = blockIdx.y, tile = blockIdx.x;     // 64 tokens per tile
    int tid = threadIdx.x;
    float4 cv[16];
#pragma unroll
    for (int j = 0; j < 16; ++j)
        cv[j] = ((const float4*)(co + ((size_t)b * 16 + j) * 1024))[tid];
    const float* cb = combine + ((size_t)b * N_ + tile * 64) * 16;
    float4* ob = (float4*)(out + ((size_t)b * N_ + tile * 64) * 1024) + tid;
    for (int it = 0; it < 64; ++it) {
        const float* cm = cb + it * 16;
        float4 acc; acc.x = 0.f; acc.y = 0.f; acc.z = 0.f; acc.w = 0.f;
#pragma unroll
        for (int j = 0; j < 16; ++j) {
            float wj = cm[j];
            acc.x += wj * cv[j].x; acc.y += wj * cv[j].y;
            acc.z += wj * cv[j].z; acc.w += wj * cv[j].w;
        }
        ob[(size_t)it * 256] = acc;
    }
}

// ---------------------------------------------------------------------------
extern "C" void kernel_launch(void* const* d_in, const int* in_sizes, int n_in,
                              void* d_out, int out_size, void* d_ws, size_t ws_size,
                              hipStream_t stream)
{
    const float* x   = (const float*)d_in[0];
    const float* phi = (const float*)d_in[2];
    const float* kg  = (const float*)d_in[3];
    const float* kb  = (const float*)d_in[4];
    const float* qg  = (const float*)d_in[5];
    const float* qb  = (const float*)d_in[6];
    const float* lng = (const float*)d_in[7];
    const float* lnb = (const float*)d_in[8];
    const float* s0  = (const float*)d_in[9];
    const float* s1  = (const float*)d_in[10];
    const float* w1  = (const float*)d_in[11];
    const float* b1  = (const float*)d_in[12];
    const float* w2  = (const float*)d_in[13];
    const float* b2  = (const float*)d_in[14];
    // occ weights d_in[15..18]: provably dead (exact-zero combine/dispatch)

    float* out = (float*)d_out;
    float* ws  = (float*)d_ws;

    float* qk       = ws;                        // 16384
    float* cj       = qk + 16384;                // 16
    float* wbuf     = cj + 16;                   // 2064 (w2|w1|C, padded)
    float* combine  = wbuf + 2064;               // 524288
    float* dispatch = combine + 524288;          // 524288
    float* partial  = dispatch + 524288;         // 2097152
    float* slotsT   = partial + 2097152;         // 131072
    float* hT       = slotsT + 131072;           // 524288
    float* co       = hT + 524288;               // 131072

    k_prep         <<<dim3(17),        dim3(64),  0, stream>>>(phi, qg, qb, lng, lnb, kg, kb, qk, cj, wbuf);
    k_route2       <<<dim3(1024),      dim3(256), 0, stream>>>(x, qk, cj, wbuf, s0, s1, combine, dispatch);
    k_slots_partial<<<dim3(16, 4, 8),  dim3(256), 0, stream>>>(x, dispatch, partial);
    k_slots_reduce <<<dim3(512),       dim3(256), 0, stream>>>(partial, slotsT);
    k_mlp1         <<<dim3(64, 8),     dim3(512), 0, stream>>>(w1, b1, slotsT, hT);
    k_mlp2         <<<dim3(32, 8),     dim3(512), 0, stream>>>(w2, b2, hT, co);
    k_out          <<<dim3(64, 8),     dim3(256), 0, stream>>>(co, combine, out);
}

// Round 3
// 341.155 us; speedup vs baseline: 2.2730x; 2.2730x over previous
//
#include <hip/hip_runtime.h>
#include <hip/hip_bf16.h>

#define B_ 8
#define N_ 4096
#define D_ 1024

// ---------------------------------------------------------------------------
// K0: prep. blocks 0..15: qk[r] = (l2norm(layernorm(phi[r]*qg+qb))) ⊙ kg,
//                         cj[r] = Σ q·kb.   block 16: w2=kg², w1=2kg·kb, C=Σkb².
// ---------------------------------------------------------------------------
__global__ __launch_bounds__(64) void k_prep(
    const float* __restrict__ phi, const float* __restrict__ qg, const float* __restrict__ qb,
    const float* __restrict__ lng, const float* __restrict__ lnb,
    const float* __restrict__ kg, const float* __restrict__ kb,
    float* __restrict__ qk, float* __restrict__ cj, float* __restrict__ wbuf)
{
    int r = blockIdx.x;        // 0..16
    int lane = threadIdx.x;    // 0..63
    if (r == 16) {
        float cacc = 0.f;
#pragma unroll
        for (int c = 0; c < 16; ++c) {
            int i = c * 64 + lane;
            float g = kg[i], b = kb[i];
            wbuf[i] = g * g;
            wbuf[1024 + i] = 2.0f * g * b;
            cacc += b * b;
        }
#pragma unroll
        for (int m = 32; m; m >>= 1) cacc += __shfl_xor(cacc, m);
        if (lane == 0) wbuf[2048] = cacc;
        return;
    }
    const float* pr = phi + (size_t)r * D_;
    float v[16];
    float s1 = 0.f;
#pragma unroll
    for (int c = 0; c < 16; ++c) {
        int i = c * 64 + lane;
        v[c] = pr[i] * qg[i] + qb[i];
        s1 += v[c];
    }
#pragma unroll
    for (int m = 32; m; m >>= 1) s1 += __shfl_xor(s1, m);
    float mu = s1 * (1.0f / D_);
    float s2 = 0.f;
#pragma unroll
    for (int c = 0; c < 16; ++c) { float dd = v[c] - mu; s2 += dd * dd; }
#pragma unroll
    for (int m = 32; m; m >>= 1) s2 += __shfl_xor(s2, m);
    float var = s2 * (1.0f / D_);
    float inv = 1.0f / sqrtf(var + 1e-5f);
    float u[16];
    float s3 = 0.f;
#pragma unroll
    for (int c = 0; c < 16; ++c) {
        int i = c * 64 + lane;
        u[c] = (v[c] - mu) * inv * lng[i] + lnb[i];
        s3 += u[c] * u[c];
    }
#pragma unroll
    for (int m = 32; m; m >>= 1) s3 += __shfl_xor(s3, m);
    float rn = 1.0f / (sqrtf(s3) + 1e-6f);
    float cacc = 0.f;
#pragma unroll
    for (int c = 0; c < 16; ++c) {
        int i = c * 64 + lane;
        float qv = u[c] * rn;
        qk[(size_t)r * D_ + i] = qv * kg[i];
        cacc += qv * kb[i];
    }
#pragma unroll
    for (int m = 32; m; m >>= 1) cacc += __shfl_xor(cacc, m);
    if (lane == 0) cj[r] = cacc;
}

// ---------------------------------------------------------------------------
// K1a: logits GEMM only (no epilogue -> low VGPR, no spills).
// 32 tokens x 8 d-splits per block; double-buffered LDS x-tile; per token
// writes 16 raw dots + weighted-norm partial to lgbuf (stride 20).
// ---------------------------------------------------------------------------
__global__ __launch_bounds__(256) void k_logits(
    const float* __restrict__ x, const float* __restrict__ qk,
    const float* __restrict__ wbuf, float* __restrict__ lgbuf)
{
    __shared__ float xs[2][32 * 68];   // 2 x 8.5 KB
    __shared__ float qs[2][16 * 64];   // 2 x 4 KB
    __shared__ float wsd[2][128];      // w2 chunk | w1 chunk

    int tid = threadIdx.x;
    int tok0 = blockIdx.x * 32;
    int tok = tid & 31, gg = tid >> 5;           // gg = 0..7

    float acc[17];
#pragma unroll
    for (int v = 0; v < 17; ++v) acc[v] = 0.f;

    float4 rx0, rx1, rq;
    float rw = 0.f;
    int r0 = tid >> 4, c40 = tid & 15;
    int r1 = 16 + r0;

    auto STAGE = [&](int dc) {
        rx0 = *(const float4*)(x + (size_t)(tok0 + r0) * D_ + dc * 64 + c40 * 4);
        rx1 = *(const float4*)(x + (size_t)(tok0 + r1) * D_ + dc * 64 + c40 * 4);
        rq  = *(const float4*)(qk + (size_t)(tid >> 4) * D_ + dc * 64 + (tid & 15) * 4);
        if (tid < 128) rw = wbuf[(size_t)(tid >> 6) * 1024 + dc * 64 + (tid & 63)];
    };
    auto WRITE = [&](int buf) {
        *(float4*)(&xs[buf][r0 * 68 + c40 * 4]) = rx0;
        *(float4*)(&xs[buf][r1 * 68 + c40 * 4]) = rx1;
        ((float4*)qs[buf])[tid] = rq;
        if (tid < 128) wsd[buf][tid] = rw;
    };
    auto COMPUTE = [&](int buf) {
        const float* xp = &xs[buf][tok * 68 + gg * 8];
        const float* qp = &qs[buf][gg * 8];
        const float* wp = &wsd[buf][gg * 8];
#pragma unroll
        for (int dl4 = 0; dl4 < 2; ++dl4) {
            float4 xv  = *(const float4*)(xp + dl4 * 4);
            float4 w2v = *(const float4*)(wp + dl4 * 4);
            float4 w1v = *(const float4*)(wp + 64 + dl4 * 4);
            acc[16] += (w2v.x * xv.x + w1v.x) * xv.x + (w2v.y * xv.y + w1v.y) * xv.y
                     + (w2v.z * xv.z + w1v.z) * xv.z + (w2v.w * xv.w + w1v.w) * xv.w;
#pragma unroll
            for (int j = 0; j < 16; ++j) {
                float4 q4 = *(const float4*)(qp + j * 64 + dl4 * 4);
                acc[j] += xv.x * q4.x + xv.y * q4.y + xv.z * q4.z + xv.w * q4.w;
            }
        }
    };

    STAGE(0);
    WRITE(0);
    int cur = 0;
#pragma unroll 1
    for (int dc = 0; dc < 16; ++dc) {
        if (dc < 15) STAGE(dc + 1);
        __syncthreads();
        COMPUTE(cur);
        if (dc < 15) WRITE(cur ^ 1);
        cur ^= 1;
    }
    __syncthreads();

    // red[tok][v][gg] : (tok*17+v)*8 + gg
    float* red = &xs[0][0];
#pragma unroll
    for (int v = 0; v < 17; ++v) red[(tok * 17 + v) * 8 + gg] = acc[v];
    __syncthreads();

#pragma unroll
    for (int it = 0; it < 3; ++it) {
        int idx = tid + it * 256;
        if (idx < 544) {
            float4 p0 = *(const float4*)(red + idx * 8);
            float4 p1 = *(const float4*)(red + idx * 8 + 4);
            float sum = ((p0.x + p0.y) + (p0.z + p0.w)) + ((p1.x + p1.y) + (p1.z + p1.w));
            int t = idx / 17, v = idx - t * 17;
            lgbuf[(size_t)(tok0 + t) * 20 + v] = sum;
        }
    }
}

// ---------------------------------------------------------------------------
// K1b: per-token epilogue. softmax over 8 core experts per slot (occ experts
// underflow to exact 0) + exact 16-way entmax15. Thread-per-token; free VGPRs.
// ---------------------------------------------------------------------------
__global__ __launch_bounds__(64) void k_epi(
    const float* __restrict__ lgbuf, const float* __restrict__ cj,
    const float* __restrict__ wbuf,
    const float* __restrict__ s0p, const float* __restrict__ s1p,
    float* __restrict__ combine, float* __restrict__ dispatch)
{
    int tok = blockIdx.x * 64 + threadIdx.x;
    const float* lp = lgbuf + (size_t)tok * 20;
    float s[17];
    float4 q0 = *(const float4*)(lp + 0);
    float4 q1 = *(const float4*)(lp + 4);
    float4 q2 = *(const float4*)(lp + 8);
    float4 q3 = *(const float4*)(lp + 12);
    s[0] = q0.x; s[1] = q0.y; s[2] = q0.z; s[3] = q0.w;
    s[4] = q1.x; s[5] = q1.y; s[6] = q1.z; s[7] = q1.w;
    s[8] = q2.x; s[9] = q2.y; s[10] = q2.z; s[11] = q2.w;
    s[12] = q3.x; s[13] = q3.y; s[14] = q3.z; s[15] = q3.w;
    s[16] = lp[16];

    float ss = s[16] + wbuf[2048];
    float rn = 1.0f / (sqrtf(ss) + 1e-6f);
    float inv0 = 1.0f / s0p[0];
    float inv1h = 0.5f / s1p[0];
    float lg[16];
#pragma unroll
    for (int j = 0; j < 16; ++j) lg[j] = (s[j] + cj[j]) * rn;

    // dispatch: softmax over 8 core experts per slot
    float dsp[16];
#pragma unroll
    for (int sl = 0; sl < 2; ++sl) {
        float a[8], m = -1e30f;
#pragma unroll
        for (int ee = 0; ee < 8; ++ee) { a[ee] = lg[2 * ee + sl] * inv0; m = fmaxf(m, a[ee]); }
        float den = 0.f;
#pragma unroll
        for (int ee = 0; ee < 8; ++ee) { a[ee] = expf(a[ee] - m); den += a[ee]; }
        float r = 1.0f / den;
#pragma unroll
        for (int ee = 0; ee < 8; ++ee) dsp[2 * ee + sl] = a[ee] * r;
    }

    // combine: exact 1.5-entmax over 16 core slot logits
    float z[16], zmax = -1e30f;
#pragma unroll
    for (int j = 0; j < 16; ++j) { z[j] = lg[j] * inv1h; zmax = fmaxf(zmax, z[j]); }
#pragma unroll
    for (int j = 0; j < 16; ++j) z[j] -= zmax;
    float zsr[16];
#pragma unroll
    for (int j = 0; j < 16; ++j) zsr[j] = z[j];
#pragma unroll
    for (int rr = 0; rr < 16; ++rr) {
#pragma unroll
        for (int jj = (rr & 1); jj + 1 < 16; jj += 2) {
            float aa = zsr[jj], bb = zsr[jj + 1];
            zsr[jj] = fmaxf(aa, bb);
            zsr[jj + 1] = fminf(aa, bb);
        }
    }
    float cs = 0.f, css = 0.f, tau_star = 0.f;
#pragma unroll
    for (int kk = 1; kk <= 16; ++kk) {
        cs += zsr[kk - 1];
        css += zsr[kk - 1] * zsr[kk - 1];
        float fk = (float)kk;
        float mean = cs / fk, msq = css / fk;
        float ssv = fk * (msq - mean * mean);
        float delta = fmaxf((1.0f - ssv) / fk, 1e-12f);
        float tau = mean - sqrtf(delta);
        tau_star = (tau <= zsr[kk - 1]) ? tau : tau_star;
    }
    float4* cw = (float4*)(combine + (size_t)tok * 16);
    float4* dw = (float4*)(dispatch + (size_t)tok * 16);
#pragma unroll
    for (int q4i = 0; q4i < 4; ++q4i) {
        float4 cv, dv;
        float t0 = fmaxf(z[q4i * 4 + 0] - tau_star, 0.f);
        float t1 = fmaxf(z[q4i * 4 + 1] - tau_star, 0.f);
        float t2 = fmaxf(z[q4i * 4 + 2] - tau_star, 0.f);
        float t3 = fmaxf(z[q4i * 4 + 3] - tau_star, 0.f);
        cv.x = t0 * t0; cv.y = t1 * t1; cv.z = t2 * t2; cv.w = t3 * t3;
        dv.x = dsp[q4i * 4 + 0]; dv.y = dsp[q4i * 4 + 1];
        dv.z = dsp[q4i * 4 + 2]; dv.w = dsp[q4i * 4 + 3];
        cw[q4i] = cv;
        dw[q4i] = dv;
    }
}

// ---------------------------------------------------------------------------
// K2b: partial slots. partial[b][nc][j][d] = sum_{n in chunk nc} disp[n][j]*x[b,n,d]
// ---------------------------------------------------------------------------
__global__ __launch_bounds__(256) void k_slots_partial(
    const float* __restrict__ x, const float* __restrict__ dispatch,
    float* __restrict__ partial)
{
    int nc = blockIdx.x, dc = blockIdx.y, b = blockIdx.z;
    int d = dc * 256 + threadIdx.x;
    const float* xb = x + (size_t)b * N_ * D_ + d;
    const float* db = dispatch + (size_t)b * N_ * 16;
    float acc[16];
#pragma unroll
    for (int j = 0; j < 16; ++j) acc[j] = 0.f;
    int n0 = nc * 256;
#pragma unroll 2
    for (int n = n0; n < n0 + 256; ++n) {
        float xv = xb[(size_t)n * D_];
        const float4* dp = (const float4*)(db + (size_t)n * 16);
        float4 q0 = dp[0], q1 = dp[1], q2 = dp[2], q3 = dp[3];
        acc[0]  += q0.x * xv; acc[1]  += q0.y * xv; acc[2]  += q0.z * xv; acc[3]  += q0.w * xv;
        acc[4]  += q1.x * xv; acc[5]  += q1.y * xv; acc[6]  += q1.z * xv; acc[7]  += q1.w * xv;
        acc[8]  += q2.x * xv; acc[9]  += q2.y * xv; acc[10] += q2.z * xv; acc[11] += q2.w * xv;
        acc[12] += q3.x * xv; acc[13] += q3.y * xv; acc[14] += q3.z * xv; acc[15] += q3.w * xv;
    }
#pragma unroll
    for (int j = 0; j < 16; ++j)
        partial[(((size_t)b * 16 + nc) * 16 + j) * 1024 + d] = acc[j];
}

// ---------------------------------------------------------------------------
// K2c: reduce partials -> slotsT[e][k][t]  (t = b*2+s)
// ---------------------------------------------------------------------------
__global__ __launch_bounds__(256) void k_slots_reduce(
    const float* __restrict__ partial, float* __restrict__ slotsT)
{
    int idx = blockIdx.x * 256 + threadIdx.x;   // 0..131071
    int t = idx & 15;
    int k = (idx >> 4) & 1023;
    int e = idx >> 14;
    int b = t >> 1, s = t & 1;
    int j = e * 2 + s;
    const float* p = partial + (((size_t)b * 16) * 16 + j) * 1024 + k;
    float sum = 0.f;
#pragma unroll
    for (int nc = 0; nc < 16; ++nc) sum += p[(size_t)nc * 16 * 1024];
    slotsT[idx] = sum;
}

// ---------------------------------------------------------------------------
// D1: h = gelu(slots @ w1 + b1), stored t-fast: hT[e][h][t]
// ---------------------------------------------------------------------------
__global__ __launch_bounds__(512) void k_mlp1(
    const float* __restrict__ w1, const float* __restrict__ b1,
    const float* __restrict__ slotsT, float* __restrict__ hT)
{
    int e = blockIdx.y;
    int col0 = blockIdx.x * 64;
    int tid = threadIdx.x;
    int cl = tid & 63;
    int p = tid >> 6;                 // 0..7
    const float* wp = w1 + ((size_t)e * 1024 + p * 128) * 4096 + col0 + cl;
    const float4* sp = (const float4*)(slotsT + ((size_t)e * 1024 + p * 128) * 16);
    float acc[16];
#pragma unroll
    for (int t = 0; t < 16; ++t) acc[t] = 0.f;
#pragma unroll 2
    for (int k = 0; k < 128; ++k) {
        float w = wp[(size_t)k * 4096];
        float4 a = sp[k * 4 + 0], bq = sp[k * 4 + 1], cq = sp[k * 4 + 2], dq = sp[k * 4 + 3];
        acc[0]  += w * a.x;  acc[1]  += w * a.y;  acc[2]  += w * a.z;  acc[3]  += w * a.w;
        acc[4]  += w * bq.x; acc[5]  += w * bq.y; acc[6]  += w * bq.z; acc[7]  += w * bq.w;
        acc[8]  += w * cq.x; acc[9]  += w * cq.y; acc[10] += w * cq.z; acc[11] += w * cq.w;
        acc[12] += w * dq.x; acc[13] += w * dq.y; acc[14] += w * dq.z; acc[15] += w * dq.w;
    }
    __shared__ float red[8 * 64 * 17];
#pragma unroll
    for (int t = 0; t < 16; ++t) red[(p * 64 + cl) * 17 + t] = acc[t];
    __syncthreads();
#pragma unroll
    for (int i = 0; i < 2; ++i) {
        int oi = tid + 512 * i;       // 0..1023
        int t = oi & 15, c = oi >> 4;
        float v = 0.f;
#pragma unroll
        for (int pp = 0; pp < 8; ++pp) v += red[(pp * 64 + c) * 17 + t];
        v += b1[(size_t)e * 4096 + col0 + c];
        v = 0.5f * v * (1.0f + erff(v * 0.70710678118654752f));   // exact GELU
        hT[((size_t)e * 4096 + col0 + c) * 16 + t] = v;
    }
}

// ---------------------------------------------------------------------------
// D2: core_out = h @ w2 + b2, stored co[b][j][d] (j = e*2+s)
// ---------------------------------------------------------------------------
__global__ __launch_bounds__(512) void k_mlp2(
    const float* __restrict__ w2, const float* __restrict__ b2,
    const float* __restrict__ hT, float* __restrict__ co)
{
    int e = blockIdx.y;
    int col0 = blockIdx.x * 32;
    int tid = threadIdx.x;
    int cl = tid & 31;
    int p = tid >> 5;                 // 0..15
    const float* wp = w2 + ((size_t)e * 4096 + p * 256) * 1024 + col0 + cl;
    const float4* hp = (const float4*)(hT + ((size_t)e * 4096 + p * 256) * 16);
    float acc[16];
#pragma unroll
    for (int t = 0; t < 16; ++t) acc[t] = 0.f;
#pragma unroll 2
    for (int k = 0; k < 256; ++k) {
        float w = wp[(size_t)k * 1024];
        float4 a = hp[k * 4 + 0], bq = hp[k * 4 + 1], cq = hp[k * 4 + 2], dq = hp[k * 4 + 3];
        acc[0]  += w * a.x;  acc[1]  += w * a.y;  acc[2]  += w * a.z;  acc[3]  += w * a.w;
        acc[4]  += w * bq.x; acc[5]  += w * bq.y; acc[6]  += w * bq.z; acc[7]  += w * bq.w;
        acc[8]  += w * cq.x; acc[9]  += w * cq.y; acc[10] += w * cq.z; acc[11] += w * cq.w;
        acc[12] += w * dq.x; acc[13] += w * dq.y; acc[14] += w * dq.z; acc[15] += w * dq.w;
    }
    __shared__ float red[16 * 32 * 17];
#pragma unroll
    for (int t = 0; t < 16; ++t) red[(p * 32 + cl) * 17 + t] = acc[t];
    __syncthreads();
    int c = tid & 31, t = tid >> 5;
    float v = 0.f;
#pragma unroll
    for (int pp = 0; pp < 16; ++pp) v += red[(pp * 32 + c) * 17 + t];
    v += b2[(size_t)e * 1024 + col0 + c];
    int bq2 = t >> 1, s = t & 1;
    co[(((size_t)bq2 * 16) + e * 2 + s) * 1024 + col0 + c] = v;
}

// ---------------------------------------------------------------------------
// KE: out[b,n,:] = sum_j combine[b,n,j] * co[b][j][:]
// ---------------------------------------------------------------------------
__global__ __launch_bounds__(256) void k_out(
    const float* __restrict__ co, const float* __restrict__ combine,
    float* __restrict__ out)
{
    int b = blockIdx.y, tile = blockIdx.x;     // 64 tokens per tile
    int tid = threadIdx.x;
    float4 cv[16];
#pragma unroll
    for (int j = 0; j < 16; ++j)
        cv[j] = ((const float4*)(co + ((size_t)b * 16 + j) * 1024))[tid];
    const float* cb = combine + ((size_t)b * N_ + tile * 64) * 16;
    float4* ob = (float4*)(out + ((size_t)b * N_ + tile * 64) * 1024) + tid;
    for (int it = 0; it < 64; ++it) {
        const float* cm = cb + it * 16;
        float4 acc; acc.x = 0.f; acc.y = 0.f; acc.z = 0.f; acc.w = 0.f;
#pragma unroll
        for (int j = 0; j < 16; ++j) {
            float wj = cm[j];
            acc.x += wj * cv[j].x; acc.y += wj * cv[j].y;
            acc.z += wj * cv[j].z; acc.w += wj * cv[j].w;
        }
        ob[(size_t)it * 256] = acc;
    }
}

// ---------------------------------------------------------------------------
extern "C" void kernel_launch(void* const* d_in, const int* in_sizes, int n_in,
                              void* d_out, int out_size, void* d_ws, size_t ws_size,
                              hipStream_t stream)
{
    const float* x   = (const float*)d_in[0];
    const float* phi = (const float*)d_in[2];
    const float* kg  = (const float*)d_in[3];
    const float* kb  = (const float*)d_in[4];
    const float* qg  = (const float*)d_in[5];
    const float* qb  = (const float*)d_in[6];
    const float* lng = (const float*)d_in[7];
    const float* lnb = (const float*)d_in[8];
    const float* s0  = (const float*)d_in[9];
    const float* s1  = (const float*)d_in[10];
    const float* w1  = (const float*)d_in[11];
    const float* b1  = (const float*)d_in[12];
    const float* w2  = (const float*)d_in[13];
    const float* b2  = (const float*)d_in[14];
    // occ weights d_in[15..18]: provably dead (exact-zero combine/dispatch)

    float* out = (float*)d_out;
    float* ws  = (float*)d_ws;

    float* qk       = ws;                        // 16384
    float* cj       = qk + 16384;                // 16
    float* wbuf     = cj + 16;                   // 2064 (w2|w1|C, padded)
    float* combine  = wbuf + 2064;               // 524288
    float* dispatch = combine + 524288;          // 524288
    float* partial  = dispatch + 524288;         // 2097152
    float* slotsT   = partial + 2097152;         // 131072
    float* hT       = slotsT + 131072;           // 524288
    float* co       = hT + 524288;               // 131072
    float* lgbuf    = partial;                   // 655360 (aliased; consumed by
                                                 // k_epi before k_slots_partial)

    k_prep         <<<dim3(17),        dim3(64),  0, stream>>>(phi, qg, qb, lng, lnb, kg, kb, qk, cj, wbuf);
    k_logits       <<<dim3(1024),      dim3(256), 0, stream>>>(x, qk, wbuf, lgbuf);
    k_epi          <<<dim3(512),       dim3(64),  0, stream>>>(lgbuf, cj, wbuf, s0, s1, combine, dispatch);
    k_slots_partial<<<dim3(16, 4, 8),  dim3(256), 0, stream>>>(x, dispatch, partial);
    k_slots_reduce <<<dim3(512),       dim3(256), 0, stream>>>(partial, slotsT);
    k_mlp1         <<<dim3(64, 8),     dim3(512), 0, stream>>>(w1, b1, slotsT, hT);
    k_mlp2         <<<dim3(32, 8),     dim3(512), 0, stream>>>(w2, b2, hT, co);
    k_out          <<<dim3(64, 8),     dim3(256), 0, stream>>>(co, combine, out);
}

// Round 5
// 246.585 us; speedup vs baseline: 3.1447x; 1.3835x over previous
//
#include <hip/hip_runtime.h>
#include <hip/hip_bf16.h>

#define B_ 8
#define N_ 4096
#define D_ 1024

// ---------------------------------------------------------------------------
// K0: prep. blocks 0..15: qk[r] = (l2norm(layernorm(phi[r]*qg+qb))) ⊙ kg,
//                         cj[r] = Σ q·kb.   block 16: w2=kg², w1=2kg·kb, C=Σkb².
// ---------------------------------------------------------------------------
__global__ __launch_bounds__(64) void k_prep(
    const float* __restrict__ phi, const float* __restrict__ qg, const float* __restrict__ qb,
    const float* __restrict__ lng, const float* __restrict__ lnb,
    const float* __restrict__ kg, const float* __restrict__ kb,
    float* __restrict__ qk, float* __restrict__ cj, float* __restrict__ wbuf)
{
    int r = blockIdx.x;        // 0..16
    int lane = threadIdx.x;    // 0..63
    if (r == 16) {
        float cacc = 0.f;
#pragma unroll
        for (int c = 0; c < 16; ++c) {
            int i = c * 64 + lane;
            float g = kg[i], b = kb[i];
            wbuf[i] = g * g;
            wbuf[1024 + i] = 2.0f * g * b;
            cacc += b * b;
        }
#pragma unroll
        for (int m = 32; m; m >>= 1) cacc += __shfl_xor(cacc, m);
        if (lane == 0) wbuf[2048] = cacc;
        return;
    }
    const float* pr = phi + (size_t)r * D_;
    float v[16];
    float s1 = 0.f;
#pragma unroll
    for (int c = 0; c < 16; ++c) {
        int i = c * 64 + lane;
        v[c] = pr[i] * qg[i] + qb[i];
        s1 += v[c];
    }
#pragma unroll
    for (int m = 32; m; m >>= 1) s1 += __shfl_xor(s1, m);
    float mu = s1 * (1.0f / D_);
    float s2 = 0.f;
#pragma unroll
    for (int c = 0; c < 16; ++c) { float dd = v[c] - mu; s2 += dd * dd; }
#pragma unroll
    for (int m = 32; m; m >>= 1) s2 += __shfl_xor(s2, m);
    float var = s2 * (1.0f / D_);
    float inv = 1.0f / sqrtf(var + 1e-5f);
    float u[16];
    float s3 = 0.f;
#pragma unroll
    for (int c = 0; c < 16; ++c) {
        int i = c * 64 + lane;
        u[c] = (v[c] - mu) * inv * lng[i] + lnb[i];
        s3 += u[c] * u[c];
    }
#pragma unroll
    for (int m = 32; m; m >>= 1) s3 += __shfl_xor(s3, m);
    float rn = 1.0f / (sqrtf(s3) + 1e-6f);
    float cacc = 0.f;
#pragma unroll
    for (int c = 0; c < 16; ++c) {
        int i = c * 64 + lane;
        float qv = u[c] * rn;
        qk[(size_t)r * D_ + i] = qv * kg[i];
        cacc += qv * kb[i];
    }
#pragma unroll
    for (int m = 32; m; m >>= 1) cacc += __shfl_xor(cacc, m);
    if (lane == 0) cj[r] = cacc;
}

// ---------------------------------------------------------------------------
// K1a: logits GEMM only (no epilogue -> low VGPR, no spills).
// ---------------------------------------------------------------------------
__global__ __launch_bounds__(256) void k_logits(
    const float* __restrict__ x, const float* __restrict__ qk,
    const float* __restrict__ wbuf, float* __restrict__ lgbuf)
{
    __shared__ float xs[2][32 * 68];
    __shared__ float qs[2][16 * 64];
    __shared__ float wsd[2][128];

    int tid = threadIdx.x;
    int tok0 = blockIdx.x * 32;
    int tok = tid & 31, gg = tid >> 5;

    float acc[17];
#pragma unroll
    for (int v = 0; v < 17; ++v) acc[v] = 0.f;

    float4 rx0, rx1, rq;
    float rw = 0.f;
    int r0 = tid >> 4, c40 = tid & 15;
    int r1 = 16 + r0;

    auto STAGE = [&](int dc) {
        rx0 = *(const float4*)(x + (size_t)(tok0 + r0) * D_ + dc * 64 + c40 * 4);
        rx1 = *(const float4*)(x + (size_t)(tok0 + r1) * D_ + dc * 64 + c40 * 4);
        rq  = *(const float4*)(qk + (size_t)(tid >> 4) * D_ + dc * 64 + (tid & 15) * 4);
        if (tid < 128) rw = wbuf[(size_t)(tid >> 6) * 1024 + dc * 64 + (tid & 63)];
    };
    auto WRITE = [&](int buf) {
        *(float4*)(&xs[buf][r0 * 68 + c40 * 4]) = rx0;
        *(float4*)(&xs[buf][r1 * 68 + c40 * 4]) = rx1;
        ((float4*)qs[buf])[tid] = rq;
        if (tid < 128) wsd[buf][tid] = rw;
    };
    auto COMPUTE = [&](int buf) {
        const float* xp = &xs[buf][tok * 68 + gg * 8];
        const float* qp = &qs[buf][gg * 8];
        const float* wp = &wsd[buf][gg * 8];
#pragma unroll
        for (int dl4 = 0; dl4 < 2; ++dl4) {
            float4 xv  = *(const float4*)(xp + dl4 * 4);
            float4 w2v = *(const float4*)(wp + dl4 * 4);
            float4 w1v = *(const float4*)(wp + 64 + dl4 * 4);
            acc[16] += (w2v.x * xv.x + w1v.x) * xv.x + (w2v.y * xv.y + w1v.y) * xv.y
                     + (w2v.z * xv.z + w1v.z) * xv.z + (w2v.w * xv.w + w1v.w) * xv.w;
#pragma unroll
            for (int j = 0; j < 16; ++j) {
                float4 q4 = *(const float4*)(qp + j * 64 + dl4 * 4);
                acc[j] += xv.x * q4.x + xv.y * q4.y + xv.z * q4.z + xv.w * q4.w;
            }
        }
    };

    STAGE(0);
    WRITE(0);
    int cur = 0;
#pragma unroll 1
    for (int dc = 0; dc < 16; ++dc) {
        if (dc < 15) STAGE(dc + 1);
        __syncthreads();
        COMPUTE(cur);
        if (dc < 15) WRITE(cur ^ 1);
        cur ^= 1;
    }
    __syncthreads();

    float* red = &xs[0][0];
#pragma unroll
    for (int v = 0; v < 17; ++v) red[(tok * 17 + v) * 8 + gg] = acc[v];
    __syncthreads();

#pragma unroll
    for (int it = 0; it < 3; ++it) {
        int idx = tid + it * 256;
        if (idx < 544) {
            float4 p0 = *(const float4*)(red + idx * 8);
            float4 p1 = *(const float4*)(red + idx * 8 + 4);
            float sum = ((p0.x + p0.y) + (p0.z + p0.w)) + ((p1.x + p1.y) + (p1.z + p1.w));
            int t = idx / 17, v = idx - t * 17;
            lgbuf[(size_t)(tok0 + t) * 20 + v] = sum;
        }
    }
}

// ---------------------------------------------------------------------------
// K1b: per-token epilogue (softmax over 8 core experts + exact entmax15).
// ---------------------------------------------------------------------------
__global__ __launch_bounds__(64) void k_epi(
    const float* __restrict__ lgbuf, const float* __restrict__ cj,
    const float* __restrict__ wbuf,
    const float* __restrict__ s0p, const float* __restrict__ s1p,
    float* __restrict__ combine, float* __restrict__ dispatch)
{
    int tok = blockIdx.x * 64 + threadIdx.x;
    const float* lp = lgbuf + (size_t)tok * 20;
    float s[17];
    float4 q0 = *(const float4*)(lp + 0);
    float4 q1 = *(const float4*)(lp + 4);
    float4 q2 = *(const float4*)(lp + 8);
    float4 q3 = *(const float4*)(lp + 12);
    s[0] = q0.x; s[1] = q0.y; s[2] = q0.z; s[3] = q0.w;
    s[4] = q1.x; s[5] = q1.y; s[6] = q1.z; s[7] = q1.w;
    s[8] = q2.x; s[9] = q2.y; s[10] = q2.z; s[11] = q2.w;
    s[12] = q3.x; s[13] = q3.y; s[14] = q3.z; s[15] = q3.w;
    s[16] = lp[16];

    float ss = s[16] + wbuf[2048];
    float rn = 1.0f / (sqrtf(ss) + 1e-6f);
    float inv0 = 1.0f / s0p[0];
    float inv1h = 0.5f / s1p[0];
    float lg[16];
#pragma unroll
    for (int j = 0; j < 16; ++j) lg[j] = (s[j] + cj[j]) * rn;

    float dsp[16];
#pragma unroll
    for (int sl = 0; sl < 2; ++sl) {
        float a[8], m = -1e30f;
#pragma unroll
        for (int ee = 0; ee < 8; ++ee) { a[ee] = lg[2 * ee + sl] * inv0; m = fmaxf(m, a[ee]); }
        float den = 0.f;
#pragma unroll
        for (int ee = 0; ee < 8; ++ee) { a[ee] = expf(a[ee] - m); den += a[ee]; }
        float r = 1.0f / den;
#pragma unroll
        for (int ee = 0; ee < 8; ++ee) dsp[2 * ee + sl] = a[ee] * r;
    }

    float z[16], zmax = -1e30f;
#pragma unroll
    for (int j = 0; j < 16; ++j) { z[j] = lg[j] * inv1h; zmax = fmaxf(zmax, z[j]); }
#pragma unroll
    for (int j = 0; j < 16; ++j) z[j] -= zmax;
    float zsr[16];
#pragma unroll
    for (int j = 0; j < 16; ++j) zsr[j] = z[j];
#pragma unroll
    for (int rr = 0; rr < 16; ++rr) {
#pragma unroll
        for (int jj = (rr & 1); jj + 1 < 16; jj += 2) {
            float aa = zsr[jj], bb = zsr[jj + 1];
            zsr[jj] = fmaxf(aa, bb);
            zsr[jj + 1] = fminf(aa, bb);
        }
    }
    float cs = 0.f, css = 0.f, tau_star = 0.f;
#pragma unroll
    for (int kk = 1; kk <= 16; ++kk) {
        cs += zsr[kk - 1];
        css += zsr[kk - 1] * zsr[kk - 1];
        float fk = (float)kk;
        float mean = cs / fk, msq = css / fk;
        float ssv = fk * (msq - mean * mean);
        float delta = fmaxf((1.0f - ssv) / fk, 1e-12f);
        float tau = mean - sqrtf(delta);
        tau_star = (tau <= zsr[kk - 1]) ? tau : tau_star;
    }
    float4* cw = (float4*)(combine + (size_t)tok * 16);
    float4* dw = (float4*)(dispatch + (size_t)tok * 16);
#pragma unroll
    for (int q4i = 0; q4i < 4; ++q4i) {
        float4 cv, dv;
        float t0 = fmaxf(z[q4i * 4 + 0] - tau_star, 0.f);
        float t1 = fmaxf(z[q4i * 4 + 1] - tau_star, 0.f);
        float t2 = fmaxf(z[q4i * 4 + 2] - tau_star, 0.f);
        float t3 = fmaxf(z[q4i * 4 + 3] - tau_star, 0.f);
        cv.x = t0 * t0; cv.y = t1 * t1; cv.z = t2 * t2; cv.w = t3 * t3;
        dv.x = dsp[q4i * 4 + 0]; dv.y = dsp[q4i * 4 + 1];
        dv.z = dsp[q4i * 4 + 2]; dv.w = dsp[q4i * 4 + 3];
        cw[q4i] = cv;
        dw[q4i] = dv;
    }
}

// ---------------------------------------------------------------------------
// K2b: partial slots, split-N. One VMEM stream (x, float2/lane), dispatch
// chunk staged in LDS. partial[b][nc][j][d], nc=32 chunks of 128 tokens.
// ---------------------------------------------------------------------------
__global__ __launch_bounds__(256) void k_slots_partial(
    const float* __restrict__ x, const float* __restrict__ dispatch,
    float* __restrict__ partial)
{
    __shared__ float sm[2048];
    int nc = blockIdx.x, dc = blockIdx.y, b = blockIdx.z;
    int tid = threadIdx.x;
    int n0 = nc * 128;
    int d0 = dc * 512 + tid * 2;
    const float4* src = (const float4*)(dispatch + ((size_t)b * N_ + n0) * 16);
    ((float4*)sm)[tid * 2] = src[tid * 2];
    ((float4*)sm)[tid * 2 + 1] = src[tid * 2 + 1];
    __syncthreads();

    const float* xp = x + ((size_t)b * N_ + n0) * D_ + d0;
    float2 acc[16];
#pragma unroll
    for (int j = 0; j < 16; ++j) { acc[j].x = 0.f; acc[j].y = 0.f; }
#pragma unroll 4
    for (int n = 0; n < 128; ++n) {
        float2 xv = *(const float2*)(xp + (size_t)n * D_);
        const float4* q4 = (const float4*)(sm + n * 16);
        float4 s0 = q4[0], s1 = q4[1], s2 = q4[2], s3 = q4[3];
        acc[0].x  += s0.x * xv.x; acc[0].y  += s0.x * xv.y;
        acc[1].x  += s0.y * xv.x; acc[1].y  += s0.y * xv.y;
        acc[2].x  += s0.z * xv.x; acc[2].y  += s0.z * xv.y;
        acc[3].x  += s0.w * xv.x; acc[3].y  += s0.w * xv.y;
        acc[4].x  += s1.x * xv.x; acc[4].y  += s1.x * xv.y;
        acc[5].x  += s1.y * xv.x; acc[5].y  += s1.y * xv.y;
        acc[6].x  += s1.z * xv.x; acc[6].y  += s1.z * xv.y;
        acc[7].x  += s1.w * xv.x; acc[7].y  += s1.w * xv.y;
        acc[8].x  += s2.x * xv.x; acc[8].y  += s2.x * xv.y;
        acc[9].x  += s2.y * xv.x; acc[9].y  += s2.y * xv.y;
        acc[10].x += s2.z * xv.x; acc[10].y += s2.z * xv.y;
        acc[11].x += s2.w * xv.x; acc[11].y += s2.w * xv.y;
        acc[12].x += s3.x * xv.x; acc[12].y += s3.x * xv.y;
        acc[13].x += s3.y * xv.x; acc[13].y += s3.y * xv.y;
        acc[14].x += s3.z * xv.x; acc[14].y += s3.z * xv.y;
        acc[15].x += s3.w * xv.x; acc[15].y += s3.w * xv.y;
    }
    float* op = partial + (((size_t)b * 32 + nc) * 16) * 1024 + d0;
#pragma unroll
    for (int j = 0; j < 16; ++j)
        *(float2*)(op + (size_t)j * 1024) = acc[j];
}

// ---------------------------------------------------------------------------
// K2c: reduce partials -> slotsT[e][k][t]  (t = b*2+s)
// ---------------------------------------------------------------------------
__global__ __launch_bounds__(256) void k_slots_reduce(
    const float* __restrict__ partial, float* __restrict__ slotsT)
{
    int idx = blockIdx.x * 256 + threadIdx.x;   // 0..131071
    int t = idx & 15;
    int k = (idx >> 4) & 1023;
    int e = idx >> 14;
    int b = t >> 1, s = t & 1;
    int j = e * 2 + s;
    const float* p = partial + ((size_t)(b * 32) * 16 + j) * 1024 + k;
    float sum = 0.f;
#pragma unroll
    for (int nc = 0; nc < 32; ++nc) sum += p[(size_t)nc * 16384];
    slotsT[idx] = sum;
}

// ---------------------------------------------------------------------------
// D1: split-K h-partials. p1[ks][e][col][t] = Σ_{k in ks} slots[t][k]*w1[k][col]
// ---------------------------------------------------------------------------
__global__ __launch_bounds__(256) void k_mlp1(
    const float* __restrict__ w1, const float* __restrict__ slotsT,
    float* __restrict__ p1)
{
    __shared__ float sm[2048];
    int cc = blockIdx.x, ks = blockIdx.y, e = blockIdx.z;
    int tid = threadIdx.x;
    int k0 = ks * 128;
    int col = cc * 512 + tid * 2;
    const float4* src = (const float4*)(slotsT + ((size_t)e * 1024 + k0) * 16);
    ((float4*)sm)[tid * 2] = src[tid * 2];
    ((float4*)sm)[tid * 2 + 1] = src[tid * 2 + 1];
    __syncthreads();

    const float* wp = w1 + (size_t)e * 1024 * 4096 + (size_t)k0 * 4096 + col;
    float2 acc[16];
#pragma unroll
    for (int t = 0; t < 16; ++t) { acc[t].x = 0.f; acc[t].y = 0.f; }
#pragma unroll 4
    for (int kk = 0; kk < 128; ++kk) {
        float2 w = *(const float2*)(wp + (size_t)kk * 4096);
        const float4* q4 = (const float4*)(sm + kk * 16);
        float4 s0 = q4[0], s1 = q4[1], s2 = q4[2], s3 = q4[3];
        acc[0].x  += s0.x * w.x; acc[0].y  += s0.x * w.y;
        acc[1].x  += s0.y * w.x; acc[1].y  += s0.y * w.y;
        acc[2].x  += s0.z * w.x; acc[2].y  += s0.z * w.y;
        acc[3].x  += s0.w * w.x; acc[3].y  += s0.w * w.y;
        acc[4].x  += s1.x * w.x; acc[4].y  += s1.x * w.y;
        acc[5].x  += s1.y * w.x; acc[5].y  += s1.y * w.y;
        acc[6].x  += s1.z * w.x; acc[6].y  += s1.z * w.y;
        acc[7].x  += s1.w * w.x; acc[7].y  += s1.w * w.y;
        acc[8].x  += s2.x * w.x; acc[8].y  += s2.x * w.y;
        acc[9].x  += s2.y * w.x; acc[9].y  += s2.y * w.y;
        acc[10].x += s2.z * w.x; acc[10].y += s2.z * w.y;
        acc[11].x += s2.w * w.x; acc[11].y += s2.w * w.y;
        acc[12].x += s3.x * w.x; acc[12].y += s3.x * w.y;
        acc[13].x += s3.y * w.x; acc[13].y += s3.y * w.y;
        acc[14].x += s3.z * w.x; acc[14].y += s3.z * w.y;
        acc[15].x += s3.w * w.x; acc[15].y += s3.w * w.y;
    }
    float* op = p1 + (((size_t)ks * 8 + e) * 4096 + col) * 16;
#pragma unroll
    for (int q = 0; q < 4; ++q) {
        float4 a, b;
        a.x = acc[q * 4 + 0].x; a.y = acc[q * 4 + 1].x; a.z = acc[q * 4 + 2].x; a.w = acc[q * 4 + 3].x;
        b.x = acc[q * 4 + 0].y; b.y = acc[q * 4 + 1].y; b.z = acc[q * 4 + 2].y; b.w = acc[q * 4 + 3].y;
        *(float4*)(op + q * 4) = a;
        *(float4*)(op + 16 + q * 4) = b;
    }
}

// ---------------------------------------------------------------------------
// D1r: hT[e][col][t] = gelu(Σ_ks p1 + b1)
// ---------------------------------------------------------------------------
__global__ __launch_bounds__(256) void k_red1(
    const float* __restrict__ p1, const float* __restrict__ b1,
    float* __restrict__ hT)
{
    int idx = blockIdx.x * 256 + threadIdx.x;    // 0..131071
    int q = idx & 3, col = (idx >> 2) & 4095, e = idx >> 14;
    const float* p = p1 + ((size_t)e * 4096 + col) * 16 + q * 4;
    float4 s; s.x = 0.f; s.y = 0.f; s.z = 0.f; s.w = 0.f;
#pragma unroll
    for (int ks = 0; ks < 8; ++ks) {
        float4 v = *(const float4*)(p + (size_t)ks * 524288);
        s.x += v.x; s.y += v.y; s.z += v.z; s.w += v.w;
    }
    float bb = b1[(size_t)e * 4096 + col];
    s.x += bb; s.y += bb; s.z += bb; s.w += bb;
    s.x = 0.5f * s.x * (1.0f + erff(s.x * 0.70710678118654752f));
    s.y = 0.5f * s.y * (1.0f + erff(s.y * 0.70710678118654752f));
    s.z = 0.5f * s.z * (1.0f + erff(s.z * 0.70710678118654752f));
    s.w = 0.5f * s.w * (1.0f + erff(s.w * 0.70710678118654752f));
    *(float4*)(hT + ((size_t)e * 4096 + col) * 16 + q * 4) = s;
}

// ---------------------------------------------------------------------------
// D2: split-K out-partials. p2[ks][e][col][t] over K=4096 in 32 chunks of 128.
// ---------------------------------------------------------------------------
__global__ __launch_bounds__(256) void k_mlp2(
    const float* __restrict__ w2, const float* __restrict__ hT,
    float* __restrict__ p2)
{
    __shared__ float sm[2048];
    int cc = blockIdx.x, ks = blockIdx.y, e = blockIdx.z;
    int tid = threadIdx.x;
    int k0 = ks * 128;
    int col = cc * 512 + tid * 2;
    const float4* src = (const float4*)(hT + ((size_t)e * 4096 + k0) * 16);
    ((float4*)sm)[tid * 2] = src[tid * 2];
    ((float4*)sm)[tid * 2 + 1] = src[tid * 2 + 1];
    __syncthreads();

    const float* wp = w2 + (size_t)e * 4096 * 1024 + (size_t)k0 * 1024 + col;
    float2 acc[16];
#pragma unroll
    for (int t = 0; t < 16; ++t) { acc[t].x = 0.f; acc[t].y = 0.f; }
#pragma unroll 4
    for (int kk = 0; kk < 128; ++kk) {
        float2 w = *(const float2*)(wp + (size_t)kk * 1024);
        const float4* q4 = (const float4*)(sm + kk * 16);
        float4 s0 = q4[0], s1 = q4[1], s2 = q4[2], s3 = q4[3];
        acc[0].x  += s0.x * w.x; acc[0].y  += s0.x * w.y;
        acc[1].x  += s0.y * w.x; acc[1].y  += s0.y * w.y;
        acc[2].x  += s0.z * w.x; acc[2].y  += s0.z * w.y;
        acc[3].x  += s0.w * w.x; acc[3].y  += s0.w * w.y;
        acc[4].x  += s1.x * w.x; acc[4].y  += s1.x * w.y;
        acc[5].x  += s1.y * w.x; acc[5].y  += s1.y * w.y;
        acc[6].x  += s1.z * w.x; acc[6].y  += s1.z * w.y;
        acc[7].x  += s1.w * w.x; acc[7].y  += s1.w * w.y;
        acc[8].x  += s2.x * w.x; acc[8].y  += s2.x * w.y;
        acc[9].x  += s2.y * w.x; acc[9].y  += s2.y * w.y;
        acc[10].x += s2.z * w.x; acc[10].y += s2.z * w.y;
        acc[11].x += s2.w * w.x; acc[11].y += s2.w * w.y;
        acc[12].x += s3.x * w.x; acc[12].y += s3.x * w.y;
        acc[13].x += s3.y * w.x; acc[13].y += s3.y * w.y;
        acc[14].x += s3.z * w.x; acc[14].y += s3.z * w.y;
        acc[15].x += s3.w * w.x; acc[15].y += s3.w * w.y;
    }
    float* op = p2 + (((size_t)ks * 8 + e) * 1024 + col) * 16;
#pragma unroll
    for (int q = 0; q < 4; ++q) {
        float4 a, b;
        a.x = acc[q * 4 + 0].x; a.y = acc[q * 4 + 1].x; a.z = acc[q * 4 + 2].x; a.w = acc[q * 4 + 3].x;
        b.x = acc[q * 4 + 0].y; b.y = acc[q * 4 + 1].y; b.z = acc[q * 4 + 2].y; b.w = acc[q * 4 + 3].y;
        *(float4*)(op + q * 4) = a;
        *(float4*)(op + 16 + q * 4) = b;
    }
}

// ---------------------------------------------------------------------------
// D2r: co[b][j][d] = Σ_ks p2 + b2   (j = e*2+s, t = b*2+s)
// Exactly 8192 threads = 32 blocks (e in 0..7). Guarded.
// ---------------------------------------------------------------------------
__global__ __launch_bounds__(256) void k_red2(
    const float* __restrict__ p2, const float* __restrict__ b2,
    float* __restrict__ co)
{
    int idx = blockIdx.x * 256 + threadIdx.x;    // 0..8191
    if (idx >= 8192) return;
    int d = idx & 1023, e = idx >> 10;           // e in 0..7
    const float* p = p2 + ((size_t)e * 1024 + d) * 16;
    float4 a0, a1, a2, a3;
    a0.x=a0.y=a0.z=a0.w=0.f; a1.x=a1.y=a1.z=a1.w=0.f;
    a2.x=a2.y=a2.z=a2.w=0.f; a3.x=a3.y=a3.z=a3.w=0.f;
#pragma unroll
    for (int ks = 0; ks < 32; ++ks) {
        const float4* v = (const float4*)(p + (size_t)ks * 131072);
        float4 v0 = v[0], v1 = v[1], v2 = v[2], v3 = v[3];
        a0.x += v0.x; a0.y += v0.y; a0.z += v0.z; a0.w += v0.w;
        a1.x += v1.x; a1.y += v1.y; a1.z += v1.z; a1.w += v1.w;
        a2.x += v2.x; a2.y += v2.y; a2.z += v2.z; a2.w += v2.w;
        a3.x += v3.x; a3.y += v3.y; a3.z += v3.z; a3.w += v3.w;
    }
    float bb = b2[(size_t)e * 1024 + d];
    float vv[16] = { a0.x, a0.y, a0.z, a0.w, a1.x, a1.y, a1.z, a1.w,
                     a2.x, a2.y, a2.z, a2.w, a3.x, a3.y, a3.z, a3.w };
#pragma unroll
    for (int t = 0; t < 16; ++t) {
        int b = t >> 1, s = t & 1;
        co[((size_t)b * 16 + e * 2 + s) * 1024 + d] = vv[t] + bb;
    }
}

// ---------------------------------------------------------------------------
// KE: out[b,n,:] = sum_j combine[b,n,j] * co[b][j][:]
// ---------------------------------------------------------------------------
__global__ __launch_bounds__(256) void k_out(
    const float* __restrict__ co, const float* __restrict__ combine,
    float* __restrict__ out)
{
    int b = blockIdx.y, tile = blockIdx.x;     // 64 tokens per tile
    int tid = threadIdx.x;
    float4 cv[16];
#pragma unroll
    for (int j = 0; j < 16; ++j)
        cv[j] = ((const float4*)(co + ((size_t)b * 16 + j) * 1024))[tid];
    const float* cb = combine + ((size_t)b * N_ + tile * 64) * 16;
    float4* ob = (float4*)(out + ((size_t)b * N_ + tile * 64) * 1024) + tid;
    for (int it = 0; it < 64; ++it) {
        const float* cm = cb + it * 16;
        float4 acc; acc.x = 0.f; acc.y = 0.f; acc.z = 0.f; acc.w = 0.f;
#pragma unroll
        for (int j = 0; j < 16; ++j) {
            float wj = cm[j];
            acc.x += wj * cv[j].x; acc.y += wj * cv[j].y;
            acc.z += wj * cv[j].z; acc.w += wj * cv[j].w;
        }
        ob[(size_t)it * 256] = acc;
    }
}

// ---------------------------------------------------------------------------
extern "C" void kernel_launch(void* const* d_in, const int* in_sizes, int n_in,
                              void* d_out, int out_size, void* d_ws, size_t ws_size,
                              hipStream_t stream)
{
    const float* x   = (const float*)d_in[0];
    const float* phi = (const float*)d_in[2];
    const float* kg  = (const float*)d_in[3];
    const float* kb  = (const float*)d_in[4];
    const float* qg  = (const float*)d_in[5];
    const float* qb  = (const float*)d_in[6];
    const float* lng = (const float*)d_in[7];
    const float* lnb = (const float*)d_in[8];
    const float* s0  = (const float*)d_in[9];
    const float* s1  = (const float*)d_in[10];
    const float* w1  = (const float*)d_in[11];
    const float* b1  = (const float*)d_in[12];
    const float* w2  = (const float*)d_in[13];
    const float* b2  = (const float*)d_in[14];
    // occ weights d_in[15..18]: provably dead (exact-zero combine/dispatch)

    float* out = (float*)d_out;
    float* ws  = (float*)d_ws;

    float* qk       = ws;                        // 16384
    float* cj       = qk + 16384;                // 16
    float* wbuf     = cj + 16;                   // 2064
    float* combine  = wbuf + 2064;               // 524288
    float* dispatch = combine + 524288;          // 524288
    float* slotsT   = dispatch + 524288;         // 131072
    float* hT       = slotsT + 131072;           // 524288
    float* co       = hT + 524288;               // 131072
    float* arena    = co + 131072;               // 4194304 floats (16.8 MB),
    // reused stream-ordered: lgbuf(655360) -> slot partials -> p1 -> p2.
    float* lgbuf    = arena;
    float* spart    = arena;
    float* p1       = arena;
    float* p2       = arena;

    k_prep         <<<dim3(17),         dim3(64),  0, stream>>>(phi, qg, qb, lng, lnb, kg, kb, qk, cj, wbuf);
    k_logits       <<<dim3(1024),       dim3(256), 0, stream>>>(x, qk, wbuf, lgbuf);
    k_epi          <<<dim3(512),        dim3(64),  0, stream>>>(lgbuf, cj, wbuf, s0, s1, combine, dispatch);
    k_slots_partial<<<dim3(32, 2, 8),   dim3(256), 0, stream>>>(x, dispatch, spart);
    k_slots_reduce <<<dim3(512),        dim3(256), 0, stream>>>(spart, slotsT);
    k_mlp1         <<<dim3(8, 8, 8),    dim3(256), 0, stream>>>(w1, slotsT, p1);
    k_red1         <<<dim3(512),        dim3(256), 0, stream>>>(p1, b1, hT);
    k_mlp2         <<<dim3(2, 32, 8),   dim3(256), 0, stream>>>(w2, hT, p2);
    k_red2         <<<dim3(32),         dim3(256), 0, stream>>>(p2, b2, co);
    k_out          <<<dim3(64, 8),      dim3(256), 0, stream>>>(co, combine, out);
}